// Round 2
// baseline (1064.956 us; speedup 1.0000x reference)
//
#include <hip/hip_runtime.h>
#include <hip/hip_bf16.h>

#define IN_CH 512
#define HID 16
#define OUT_CH 64
#define CAP 20480   // bucket capacity: mean 16384, sigma ~128 -> +32 sigma
#define PE 8192     // edges per partition block

typedef __attribute__((ext_vector_type(8))) short bf16x8;
typedef __attribute__((ext_vector_type(4))) float f32x4;

__device__ inline unsigned short f2bf(float f) {   // RNE truncate to bf16
    unsigned int u = __float_as_uint(f);
    return (unsigned short)((u + 0x7fffu + ((u >> 16) & 1u)) >> 16);
}

union A8 { bf16x8 v; short2 p[4]; };
__device__ inline short2 pk2(float a, float b) {
    union { __hip_bfloat162 h; short2 s; } u;
    u.h = __float22bfloat162_rn(make_float2(a, b));
    return u.s;
}

// ---------------- init bucket cursors ----------------
__global__ void k_init(int* __restrict__ cursors, int nbk) {
    int i = threadIdx.x;
    if (i < nbk) cursors[i] = i * CAP;
}

// ---------------- Phase 1: partition edges into 512-node buckets ----------------
// Single global read of the edge list (rows held in regs). Edges are sorted by
// bucket into an LDS staging buffer, then written out bucket-contiguous ->
// coalesced global stores (the old version scattered 8B writes to ~64 random
// buckets per wave, ~8x write amplification).
__global__ __launch_bounds__(1024) void k_partition(const int* __restrict__ ei1, const float* __restrict__ w1, int E1,
                                                    const int* __restrict__ ei2, const float* __restrict__ w2, int E2,
                                                    int* __restrict__ cursors,
                                                    uint2* __restrict__ packed, int Et) {
    __shared__ int hist[256];
    __shared__ int sc[256];
    __shared__ int lbase[256];
    __shared__ int gbase[256];
    __shared__ int lcur[256];
    __shared__ uint2 stage[PE];          // 64 KB
    __shared__ unsigned char bkt[PE];    // slot -> bucket (8 KB)
    int tid = threadIdx.x;
    int e0 = blockIdx.x * PE;
    if (tid < 256) hist[tid] = 0;
    __syncthreads();
    int r[8];
    #pragma unroll
    for (int j = 0; j < 8; ++j) {
        int e = e0 + j * 1024 + tid;
        int rr = -1;
        if (e < Et) rr = (e < E1) ? ei1[e] : ei2[e - E1];
        r[j] = rr;
        if (rr >= 0) atomicAdd(&hist[rr >> 9], 1);
    }
    __syncthreads();
    int v = (tid < 256) ? hist[tid] : 0;
    if (tid < 256) sc[tid] = v;
    __syncthreads();
    for (int off = 1; off < 256; off <<= 1) {
        int t = (tid >= off && tid < 256) ? sc[tid - off] : 0;
        __syncthreads();
        if (tid < 256) sc[tid] += t;
        __syncthreads();
    }
    if (tid < 256) {
        int ex = sc[tid] - v;            // exclusive local base
        lbase[tid] = ex;
        lcur[tid] = ex;
        gbase[tid] = (v > 0) ? atomicAdd(&cursors[tid], v) : 0;  // one global atomic per (block,bucket)
    }
    __syncthreads();
    // place cols/weights into LDS stage, bucket-sorted
    #pragma unroll
    for (int j = 0; j < 8; ++j) {
        if (r[j] >= 0) {
            int e = e0 + j * 1024 + tid;
            int cc; float ww;
            if (e < E1) { cc = ei1[e + E1]; ww = w1[e]; }
            else        { int f = e - E1; cc = ei2[f + E2]; ww = w2[f]; }
            int bk = r[j] >> 9;
            int pos = atomicAdd(&lcur[bk], 1);
            stage[pos] = make_uint2(((unsigned)(r[j] & 511) << 17) | (unsigned)cc,
                                    __float_as_uint(ww));
            bkt[pos] = (unsigned char)bk;
        }
    }
    __syncthreads();
    // coalesced write-out: consecutive slots in the same bucket hit consecutive
    // global addresses (bucket runs avg ~32 entries)
    int nv = min(PE, Et - e0);
    for (int i = tid; i < nv; i += 1024) {
        int bk = bkt[i];
        packed[(size_t)gbase[bk] + (i - lbase[bk])] = stage[i];
    }
}

// ---------------- Phase 2: per-bucket degree -> dinv ----------------
__global__ __launch_bounds__(1024) void k_deg(const uint2* __restrict__ packed,
                                              const int* __restrict__ cursors,
                                              float* __restrict__ dinv, int N) {
    __shared__ float ldeg[512];
    int b = blockIdx.x, tid = threadIdx.x;
    if (tid < 512) ldeg[tid] = 0.f;
    __syncthreads();
    int M = cursors[b] - b * CAP;
    const uint2* pk = packed + (size_t)b * CAP;
    for (int i = tid; i < M; i += 1024) {
        uint2 u = pk[i];
        atomicAdd(&ldeg[u.x >> 17], __uint_as_float(u.y));
    }
    __syncthreads();
    if (tid < 512) {
        int node = b * 512 + tid;
        if (node < N) {
            float d = ldeg[tid];
            dinv[node] = (d > 0.f) ? rsqrtf(fmaxf(d, 1e-12f)) : 0.f;
        }
    }
}

// ---------------- prep: W1 -> bf16, swizzled into B-fragment order ----------------
// W1s[(kc*64+lane)*8 + j] = bf16(W1[(kc*32 + (lane>>4)*8 + j)*16 + (lane&15)])
__global__ void k_prep(const float* __restrict__ W1, unsigned short* __restrict__ W1s) {
    for (int p = threadIdx.x; p < 1024; p += 256) {
        int kc = p >> 6, lane = p & 63;
        int q = lane >> 4, m = lane & 15;
        int k0 = kc * 32 + q * 8;
        unsigned v[8];
        #pragma unroll
        for (int j = 0; j < 8; ++j) v[j] = f2bf(W1[(k0 + j) * HID + m]);
        uint4 o;
        o.x = v[0] | (v[1] << 16); o.y = v[2] | (v[3] << 16);
        o.z = v[4] | (v[5] << 16); o.w = v[6] | (v[7] << 16);
        ((uint4*)W1s)[p] = o;
    }
}

// ---------------- h1s = dinv * (x @ W1) via MFMA bf16 ----------------
__global__ __launch_bounds__(256) void k_gemm1(const float* __restrict__ x,
                                               const unsigned short* __restrict__ W1s,
                                               const float* __restrict__ dinv,
                                               float* __restrict__ h1s, int n) {
    int wave = threadIdx.x >> 6, lane = threadIdx.x & 63;
    int tiles = (n + 15) >> 4;
    int t = blockIdx.x * 4 + wave;
    if (t >= tiles) return;

    int m = lane & 15, quad = lane >> 4;

    const bf16x8* Wv = (const bf16x8*)W1s;
    bf16x8 Bf[16];
    #pragma unroll
    for (int kc = 0; kc < 16; ++kc) Bf[kc] = Wv[kc * 64 + lane];   // 16B contiguous

    int row = t * 16 + m;
    int rl = min(row, n - 1);
    const float4* xr = (const float4*)(x + (size_t)rl * IN_CH + quad * 8);

    f32x4 acc = {0.f, 0.f, 0.f, 0.f};
    #pragma unroll
    for (int kc = 0; kc < 16; ++kc) {
        float4 v0 = xr[kc * 8];
        float4 v1 = xr[kc * 8 + 1];
        A8 a;
        a.p[0] = pk2(v0.x, v0.y); a.p[1] = pk2(v0.z, v0.w);
        a.p[2] = pk2(v1.x, v1.y); a.p[3] = pk2(v1.z, v1.w);
        acc = __builtin_amdgcn_mfma_f32_16x16x32_bf16(a.v, Bf[kc], acc, 0, 0, 0);
    }

    int base = t * 16 + quad * 4;
    #pragma unroll
    for (int r = 0; r < 4; ++r) {
        int orow = base + r;
        if (orow < n) h1s[(size_t)orow * HID + m] = dinv[orow] * acc[r];
    }
}

// ---------------- layer1 aggregate: edge-parallel LDS scatter per bucket ----------------
// One block per 512-node bucket. 4 lanes per edge gather float4 of h1s[col],
// scatter-add into padded acc[512][17] (stride 17 spreads banks). Epilogue
// fuses bias + relu + both dinv scalings.
__global__ __launch_bounds__(1024) void k_agg1(const float* __restrict__ h1s,
                                               const uint2* __restrict__ packed,
                                               const int* __restrict__ cursors,
                                               const float* __restrict__ dinv,
                                               const float* __restrict__ b1,
                                               float* __restrict__ out1s, int N) {
    __shared__ float accs[512 * 17];
    int b = blockIdx.x, tid = threadIdx.x;
    for (int i = tid; i < 512 * 17; i += 1024) accs[i] = 0.f;
    __syncthreads();
    int M = cursors[b] - b * CAP;
    const uint2* pk = packed + (size_t)b * CAP;
    int c4 = tid & 3;
    for (int e = tid >> 2; e < M; e += 256) {
        uint2 u = pk[e];
        int lr = u.x >> 17;
        int cc = u.x & 0x1FFFF;
        float w = __uint_as_float(u.y);
        float4 hv = ((const float4*)(h1s + (size_t)cc * HID))[c4];
        int a0 = lr * 17 + c4 * 4;
        atomicAdd(&accs[a0 + 0], w * hv.x);
        atomicAdd(&accs[a0 + 1], w * hv.y);
        atomicAdd(&accs[a0 + 2], w * hv.z);
        atomicAdd(&accs[a0 + 3], w * hv.w);
    }
    __syncthreads();
    if (tid < 512) {
        int node = b * 512 + tid;
        if (node < N) {
            float dv = dinv[node];
            float4* dst = (float4*)(out1s + (size_t)node * HID);
            #pragma unroll
            for (int q = 0; q < 4; ++q) {
                float4 bb = ((const float4*)b1)[q];
                float4 o;
                o.x = fmaxf(fmaf(dv, accs[tid * 17 + q * 4 + 0], bb.x), 0.f) * dv;
                o.y = fmaxf(fmaf(dv, accs[tid * 17 + q * 4 + 1], bb.y), 0.f) * dv;
                o.z = fmaxf(fmaf(dv, accs[tid * 17 + q * 4 + 2], bb.z), 0.f) * dv;
                o.w = fmaxf(fmaf(dv, accs[tid * 17 + q * 4 + 3], bb.w), 0.f) * dv;
                dst[q] = o;
            }
        }
    }
}

// ---------------- layer2: bucket aggregate -> 16->64 GEMM -> log_softmax ----------------
__global__ __launch_bounds__(1024) void k_layer2(const float* __restrict__ out1s,
                                                 const uint2* __restrict__ packed,
                                                 const int* __restrict__ cursors,
                                                 const float* __restrict__ dinv,
                                                 const float* __restrict__ W2,
                                                 const float* __restrict__ b2,
                                                 float* __restrict__ out, int N) {
    __shared__ float accs[512 * 17];
    __shared__ float W2l[HID * OUT_CH];
    __shared__ float b2l[OUT_CH];
    int b = blockIdx.x, tid = threadIdx.x;
    for (int i = tid; i < 512 * 17; i += 1024) accs[i] = 0.f;
    if (tid < HID * OUT_CH) W2l[tid] = W2[tid];   // exactly 1024 elems
    if (tid < OUT_CH) b2l[tid] = b2[tid];
    __syncthreads();
    int M = cursors[b] - b * CAP;
    const uint2* pk = packed + (size_t)b * CAP;
    int c4 = tid & 3;
    for (int e = tid >> 2; e < M; e += 256) {
        uint2 u = pk[e];
        int lr = u.x >> 17;
        int cc = u.x & 0x1FFFF;
        float w = __uint_as_float(u.y);
        float4 hv = ((const float4*)(out1s + (size_t)cc * HID))[c4];
        int a0 = lr * 17 + c4 * 4;
        atomicAdd(&accs[a0 + 0], w * hv.x);
        atomicAdd(&accs[a0 + 1], w * hv.y);
        atomicAdd(&accs[a0 + 2], w * hv.z);
        atomicAdd(&accs[a0 + 3], w * hv.w);
    }
    __syncthreads();
    // epilogue: 2 threads per node, 32 output channels each
    int nd = tid >> 1, half = tid & 1, ch0 = half * 32;
    int node = b * 512 + nd;
    if (node < N) {
        float dv = dinv[node];
        float a[16];
        #pragma unroll
        for (int k = 0; k < 16; ++k) a[k] = dv * accs[nd * 17 + k];
        float vv[32];
        #pragma unroll
        for (int c = 0; c < 32; ++c) vv[c] = b2l[ch0 + c];
        #pragma unroll
        for (int k = 0; k < 16; ++k) {
            #pragma unroll
            for (int c = 0; c < 32; ++c)
                vv[c] = fmaf(a[k], W2l[k * OUT_CH + ch0 + c], vv[c]);
        }
        float m = vv[0];
        #pragma unroll
        for (int c = 1; c < 32; ++c) m = fmaxf(m, vv[c]);
        m = fmaxf(m, __shfl_xor(m, 1, 64));      // partner lane = other half
        float s = 0.f;
        #pragma unroll
        for (int c = 0; c < 32; ++c) s += __expf(vv[c] - m);
        s += __shfl_xor(s, 1, 64);
        float ls = __logf(s);
        float4* dst = (float4*)(out + (size_t)node * OUT_CH + ch0);
        #pragma unroll
        for (int q = 0; q < 8; ++q) {
            float4 o;
            o.x = vv[q * 4 + 0] - m - ls;
            o.y = vv[q * 4 + 1] - m - ls;
            o.z = vv[q * 4 + 2] - m - ls;
            o.w = vv[q * 4 + 3] - m - ls;
            dst[q] = o;
        }
    }
}

extern "C" void kernel_launch(void* const* d_in, const int* in_sizes, int n_in,
                              void* d_out, int out_size, void* d_ws, size_t ws_size,
                              hipStream_t stream) {
    const float* x   = (const float*)d_in[0];
    const int*   ei1 = (const int*)d_in[1];
    const float* w1  = (const float*)d_in[2];
    const int*   ei2 = (const int*)d_in[3];
    const float* w2  = (const float*)d_in[4];
    const float* W1  = (const float*)d_in[5];
    const float* b1  = (const float*)d_in[6];
    const float* W2  = (const float*)d_in[7];
    const float* b2  = (const float*)d_in[8];
    int N  = in_sizes[0] / IN_CH;
    int E1 = in_sizes[2];
    int E2 = in_sizes[4];
    int Et = E1 + E2;
    float* out = (float*)d_out;
    int nbk = (N + 511) >> 9;   // 196 buckets of 512 nodes

    // workspace layout (packed lives through layer2 now -> no aliasing)
    char* p = (char*)d_ws;
    int*   cursors  = (int*)p;   p += 1024;
    float* dinv     = (float*)p; p += (size_t)N * 4;
    unsigned short* W1s = (unsigned short*)p; p += IN_CH * HID * 2;
    uint2* packed   = (uint2*)p; p += (size_t)nbk * CAP * 8;   // 32.1 MB
    float* h1s      = (float*)p; p += (size_t)N * HID * 4;     // 6.4 MB
    float* out1s    = (float*)p;                               // 6.4 MB

    k_init<<<1, 256, 0, stream>>>(cursors, nbk);
    k_prep<<<1, 256, 0, stream>>>(W1, W1s);
    k_partition<<<(Et + PE - 1) / PE, 1024, 0, stream>>>(ei1, w1, E1, ei2, w2, E2,
                                                         cursors, packed, Et);
    k_deg<<<nbk, 1024, 0, stream>>>(packed, cursors, dinv, N);
    int tiles = (N + 15) / 16;
    k_gemm1<<<(tiles + 3) / 4, 256, 0, stream>>>(x, W1s, dinv, h1s, N);
    k_agg1<<<nbk, 1024, 0, stream>>>(h1s, packed, cursors, dinv, b1, out1s, N);
    k_layer2<<<nbk, 1024, 0, stream>>>(out1s, packed, cursors, dinv, W2, b2, out, N);
}

// Round 4
// 517.162 us; speedup vs baseline: 2.0592x; 2.0592x over previous
//
#include <hip/hip_runtime.h>
#include <hip/hip_bf16.h>

#define IN_CH 512
#define HID 16
#define OUT_CH 64
#define CAP 20480   // bucket capacity: mean 16384, sigma ~128 -> +32 sigma
#define PE 8192     // edges per partition block

typedef __attribute__((ext_vector_type(8))) short bf16x8;
typedef __attribute__((ext_vector_type(4))) float f32x4;

__device__ inline unsigned short f2bf(float f) {   // RNE truncate to bf16
    unsigned int u = __float_as_uint(f);
    return (unsigned short)((u + 0x7fffu + ((u >> 16) & 1u)) >> 16);
}

union A8 { bf16x8 v; short2 p[4]; };
__device__ inline short2 pk2(float a, float b) {
    union { __hip_bfloat162 h; short2 s; } u;
    u.h = __float22bfloat162_rn(make_float2(a, b));
    return u.s;
}

// ---------------- init bucket cursors ----------------
__global__ void k_init(int* __restrict__ cursors, int nbk) {
    int i = threadIdx.x;
    if (i < nbk) cursors[i] = i * CAP;
}

// ---------------- Phase 1: partition edges into 512-node buckets ----------------
// Single global read of the edge list (rows held in regs). Edges are sorted by
// bucket into an LDS staging buffer, then written out bucket-contiguous ->
// coalesced global stores. (Proven correct in round 2; old 2-pass version
// scattered 8B writes to ~64 random buckets per wave, ~8x write amplification.)
__global__ __launch_bounds__(1024) void k_partition(const int* __restrict__ ei1, const float* __restrict__ w1, int E1,
                                                    const int* __restrict__ ei2, const float* __restrict__ w2, int E2,
                                                    int* __restrict__ cursors,
                                                    uint2* __restrict__ packed, int Et) {
    __shared__ int hist[256];
    __shared__ int sc[256];
    __shared__ int lbase[256];
    __shared__ int gbase[256];
    __shared__ int lcur[256];
    __shared__ uint2 stage[PE];          // 64 KB
    __shared__ unsigned char bkt[PE];    // slot -> bucket (8 KB)
    int tid = threadIdx.x;
    int e0 = blockIdx.x * PE;
    if (tid < 256) hist[tid] = 0;
    __syncthreads();
    int r[8];
    #pragma unroll
    for (int j = 0; j < 8; ++j) {
        int e = e0 + j * 1024 + tid;
        int rr = -1;
        if (e < Et) rr = (e < E1) ? ei1[e] : ei2[e - E1];
        r[j] = rr;
        if (rr >= 0) atomicAdd(&hist[rr >> 9], 1);
    }
    __syncthreads();
    int v = (tid < 256) ? hist[tid] : 0;
    if (tid < 256) sc[tid] = v;
    __syncthreads();
    for (int off = 1; off < 256; off <<= 1) {
        int t = (tid >= off && tid < 256) ? sc[tid - off] : 0;
        __syncthreads();
        if (tid < 256) sc[tid] += t;
        __syncthreads();
    }
    if (tid < 256) {
        int ex = sc[tid] - v;            // exclusive local base
        lbase[tid] = ex;
        lcur[tid] = ex;
        gbase[tid] = (v > 0) ? atomicAdd(&cursors[tid], v) : 0;  // one global atomic per (block,bucket)
    }
    __syncthreads();
    // place cols/weights into LDS stage, bucket-sorted
    #pragma unroll
    for (int j = 0; j < 8; ++j) {
        if (r[j] >= 0) {
            int e = e0 + j * 1024 + tid;
            int cc; float ww;
            if (e < E1) { cc = ei1[e + E1]; ww = w1[e]; }
            else        { int f = e - E1; cc = ei2[f + E2]; ww = w2[f]; }
            int bk = r[j] >> 9;
            int pos = atomicAdd(&lcur[bk], 1);
            stage[pos] = make_uint2(((unsigned)(r[j] & 511) << 17) | (unsigned)cc,
                                    __float_as_uint(ww));
            bkt[pos] = (unsigned char)bk;
        }
    }
    __syncthreads();
    // coalesced write-out: consecutive slots in the same bucket hit consecutive
    // global addresses (bucket runs avg ~32 entries)
    int nv = min(PE, Et - e0);
    for (int i = tid; i < nv; i += 1024) {
        int bk = bkt[i];
        packed[(size_t)gbase[bk] + (i - lbase[bk])] = stage[i];
    }
}

// ---------------- Phase 2: bucket totals -> dense CSR base offsets ----------------
__global__ void k_bucket_scan(const int* __restrict__ cursors, int* __restrict__ cbase, int nbk) {
    __shared__ int s[256];
    int tid = threadIdx.x;
    int v = (tid < nbk) ? (cursors[tid] - tid * CAP) : 0;
    s[tid] = v;
    __syncthreads();
    for (int off = 1; off < 256; off <<= 1) {
        int t = (tid >= off) ? s[tid - off] : 0;
        __syncthreads();
        s[tid] += t;
        __syncthreads();
    }
    if (tid < nbk) cbase[tid] = s[tid] - v;  // exclusive
}

// ---------------- Phase 3: per-bucket CSR build (pure streaming) ----------------
__global__ __launch_bounds__(1024) void k_buildcsr(const uint2* __restrict__ packed,
                                                   const int* __restrict__ cursors,
                                                   const int* __restrict__ cbase,
                                                   int* __restrict__ rowstart, int* __restrict__ cnt,
                                                   float* __restrict__ dinv, int2* __restrict__ csr, int N) {
    __shared__ int lcnt[512];
    __shared__ int lcur[512];
    __shared__ int lscan[512];
    __shared__ float ldeg[512];
    int b = blockIdx.x, tid = threadIdx.x;
    int M = cursors[b] - b * CAP;
    const uint2* pk = packed + (size_t)b * CAP;
    if (tid < 512) { lcnt[tid] = 0; ldeg[tid] = 0.f; }
    __syncthreads();
    for (int i = tid; i < M; i += 1024) atomicAdd(&lcnt[pk[i].x >> 17], 1);
    __syncthreads();
    int v = (tid < 512) ? lcnt[tid] : 0;
    if (tid < 512) lscan[tid] = v;
    __syncthreads();
    for (int off = 1; off < 512; off <<= 1) {
        int t = (tid >= off && tid < 512) ? lscan[tid - off] : 0;
        __syncthreads();
        if (tid < 512) lscan[tid] += t;
        __syncthreads();
    }
    int cb = cbase[b];
    if (tid < 512) {
        int ex = lscan[tid] - v;
        lcur[tid] = cb + ex;          // direct global cursor
        int node = b * 512 + tid;
        if (node < N) { rowstart[node] = cb + ex; cnt[node] = v; }
    }
    __syncthreads();
    for (int i = tid; i < M; i += 1024) {
        uint2 u = pk[i];
        int lr = u.x >> 17;
        int c  = u.x & 0x1FFFF;
        int p = atomicAdd(&lcur[lr], 1);
        csr[p] = make_int2(c, (int)u.y);
        atomicAdd(&ldeg[lr], __uint_as_float(u.y));
    }
    __syncthreads();
    if (tid < 512) {
        int node = b * 512 + tid;
        if (node < N) {
            float d = ldeg[tid];
            dinv[node] = (d > 0.f) ? rsqrtf(fmaxf(d, 1e-12f)) : 0.f;
        }
    }
}

// ---------------- prep: W1 -> bf16, swizzled into B-fragment order ----------------
// W1s[(kc*64+lane)*8 + j] = bf16(W1[(kc*32 + (lane>>4)*8 + j)*16 + (lane&15)])
__global__ void k_prep(const float* __restrict__ W1, unsigned short* __restrict__ W1s) {
    for (int p = threadIdx.x; p < 1024; p += 256) {
        int kc = p >> 6, lane = p & 63;
        int q = lane >> 4, m = lane & 15;
        int k0 = kc * 32 + q * 8;
        unsigned v[8];
        #pragma unroll
        for (int j = 0; j < 8; ++j) v[j] = f2bf(W1[(k0 + j) * HID + m]);
        uint4 o;
        o.x = v[0] | (v[1] << 16); o.y = v[2] | (v[3] << 16);
        o.z = v[4] | (v[5] << 16); o.w = v[6] | (v[7] << 16);
        ((uint4*)W1s)[p] = o;
    }
}

// ---------------- h1s = dinv * (x @ W1) via MFMA bf16 ----------------
__global__ __launch_bounds__(256) void k_gemm1(const float* __restrict__ x,
                                               const unsigned short* __restrict__ W1s,
                                               const float* __restrict__ dinv,
                                               float* __restrict__ h1s, int n) {
    int wave = threadIdx.x >> 6, lane = threadIdx.x & 63;
    int tiles = (n + 15) >> 4;
    int t = blockIdx.x * 4 + wave;
    if (t >= tiles) return;

    int m = lane & 15, quad = lane >> 4;

    const bf16x8* Wv = (const bf16x8*)W1s;
    bf16x8 Bf[16];
    #pragma unroll
    for (int kc = 0; kc < 16; ++kc) Bf[kc] = Wv[kc * 64 + lane];   // 16B contiguous

    int row = t * 16 + m;
    int rl = min(row, n - 1);
    const float4* xr = (const float4*)(x + (size_t)rl * IN_CH + quad * 8);

    f32x4 acc = {0.f, 0.f, 0.f, 0.f};
    #pragma unroll
    for (int kc = 0; kc < 16; ++kc) {
        float4 v0 = xr[kc * 8];
        float4 v1 = xr[kc * 8 + 1];
        A8 a;
        a.p[0] = pk2(v0.x, v0.y); a.p[1] = pk2(v0.z, v0.w);
        a.p[2] = pk2(v1.x, v1.y); a.p[3] = pk2(v1.z, v1.w);
        acc = __builtin_amdgcn_mfma_f32_16x16x32_bf16(a.v, Bf[kc], acc, 0, 0, 0);
    }

    int base = t * 16 + quad * 4;
    #pragma unroll
    for (int r = 0; r < 4; ++r) {
        int orow = base + r;
        if (orow < n) h1s[(size_t)orow * HID + m] = dinv[orow] * acc[r];
    }
}

// ---------------- out1s = dinv * relu(dinv*aggregate(h1s) + b1) ----------------
// lane = (slot=lane>>2 edge slot, c4=lane&3 channel quad). 16 edges in flight,
// float4 gathers.
__global__ __launch_bounds__(256) void k_agg1(const float* __restrict__ h1s,
                                              const int2* __restrict__ csr,
                                              const int* __restrict__ rowstart,
                                              const int* __restrict__ cnt,
                                              const float* __restrict__ dinv,
                                              const float* __restrict__ b1,
                                              float* __restrict__ out1s, int n) {
    int wave = threadIdx.x >> 6, lane = threadIdx.x & 63;
    int node = blockIdx.x * 4 + wave;
    if (node >= n) return;
    int slot = lane >> 2, c4 = lane & 3;
    const int2* ce = csr + rowstart[node];
    int deg = cnt[node];
    f32x4 acc = {0.f, 0.f, 0.f, 0.f};
    for (int i = slot; i < deg; i += 16) {
        int2 e = ce[i];
        float w = __int_as_float(e.y);
        float4 hv = ((const float4*)(h1s + (size_t)e.x * HID))[c4];
        acc[0] = fmaf(w, hv.x, acc[0]); acc[1] = fmaf(w, hv.y, acc[1]);
        acc[2] = fmaf(w, hv.z, acc[2]); acc[3] = fmaf(w, hv.w, acc[3]);
    }
    #pragma unroll
    for (int off = 4; off < 64; off <<= 1) {
        acc[0] += __shfl_xor(acc[0], off, 64);
        acc[1] += __shfl_xor(acc[1], off, 64);
        acc[2] += __shfl_xor(acc[2], off, 64);
        acc[3] += __shfl_xor(acc[3], off, 64);
    }
    if (lane < 4) {
        float dv = dinv[node];
        float4 bb = ((const float4*)b1)[c4];
        float4 o;
        o.x = fmaxf(fmaf(dv, acc[0], bb.x), 0.f) * dv;
        o.y = fmaxf(fmaf(dv, acc[1], bb.y), 0.f) * dv;
        o.z = fmaxf(fmaf(dv, acc[2], bb.z), 0.f) * dv;
        o.w = fmaxf(fmaf(dv, acc[3], bb.w), 0.f) * dv;
        ((float4*)(out1s + (size_t)node * HID))[c4] = o;
    }
}

// ---------------- layer2: agg(out1s) -> 16->64 GEMM -> log_softmax ----------------
__global__ __launch_bounds__(256) void k_layer2(const float* __restrict__ out1s,
                                                const int2* __restrict__ csr,
                                                const int* __restrict__ rowstart,
                                                const int* __restrict__ cnt,
                                                const float* __restrict__ dinv,
                                                const float* __restrict__ W2,
                                                const float* __restrict__ b2,
                                                float* __restrict__ out, int n) {
    __shared__ float W2l[HID * OUT_CH];
    for (int i = threadIdx.x; i < HID * OUT_CH; i += 256) W2l[i] = W2[i];
    __syncthreads();

    int wave = threadIdx.x >> 6, lane = threadIdx.x & 63;
    int node = blockIdx.x * 4 + wave;
    if (node >= n) return;
    int slot = lane >> 2, c4 = lane & 3;
    const int2* ce = csr + rowstart[node];
    int deg = cnt[node];
    f32x4 acc = {0.f, 0.f, 0.f, 0.f};
    for (int i = slot; i < deg; i += 16) {
        int2 e = ce[i];
        float w = __int_as_float(e.y);
        float4 hv = ((const float4*)(out1s + (size_t)e.x * HID))[c4];
        acc[0] = fmaf(w, hv.x, acc[0]); acc[1] = fmaf(w, hv.y, acc[1]);
        acc[2] = fmaf(w, hv.z, acc[2]); acc[3] = fmaf(w, hv.w, acc[3]);
    }
    #pragma unroll
    for (int off = 4; off < 64; off <<= 1) {
        acc[0] += __shfl_xor(acc[0], off, 64);
        acc[1] += __shfl_xor(acc[1], off, 64);
        acc[2] += __shfl_xor(acc[2], off, 64);
        acc[3] += __shfl_xor(acc[3], off, 64);
    }
    float dv = dinv[node];
    acc[0] *= dv; acc[1] *= dv; acc[2] *= dv; acc[3] *= dv;
    // lane j needs all 16 agg values: lane gg (gg<4) holds channels 4gg..4gg+3
    float v = b2[lane];
    #pragma unroll
    for (int gg = 0; gg < 4; ++gg) {
        float a0 = __shfl(acc[0], gg, 64);
        float a1 = __shfl(acc[1], gg, 64);
        float a2 = __shfl(acc[2], gg, 64);
        float a3 = __shfl(acc[3], gg, 64);
        v = fmaf(a0, W2l[(4 * gg + 0) * OUT_CH + lane], v);
        v = fmaf(a1, W2l[(4 * gg + 1) * OUT_CH + lane], v);
        v = fmaf(a2, W2l[(4 * gg + 2) * OUT_CH + lane], v);
        v = fmaf(a3, W2l[(4 * gg + 3) * OUT_CH + lane], v);
    }
    float m = v;
    #pragma unroll
    for (int off = 32; off; off >>= 1) m = fmaxf(m, __shfl_xor(m, off, 64));
    float ex = __expf(v - m);
    float s = ex;
    #pragma unroll
    for (int off = 32; off; off >>= 1) s += __shfl_xor(s, off, 64);
    out[(size_t)node * OUT_CH + lane] = (v - m) - __logf(s);
}

extern "C" void kernel_launch(void* const* d_in, const int* in_sizes, int n_in,
                              void* d_out, int out_size, void* d_ws, size_t ws_size,
                              hipStream_t stream) {
    const float* x   = (const float*)d_in[0];
    const int*   ei1 = (const int*)d_in[1];
    const float* w1  = (const float*)d_in[2];
    const int*   ei2 = (const int*)d_in[3];
    const float* w2  = (const float*)d_in[4];
    const float* W1  = (const float*)d_in[5];
    const float* b1  = (const float*)d_in[6];
    const float* W2  = (const float*)d_in[7];
    const float* b2  = (const float*)d_in[8];
    int N  = in_sizes[0] / IN_CH;
    int E1 = in_sizes[2];
    int E2 = in_sizes[4];
    int Et = E1 + E2;
    float* out = (float*)d_out;
    int nbk = (N + 511) >> 9;   // 196 buckets of 512 nodes

    // workspace layout; packed (dead after k_buildcsr) aliases h1s+out1s
    char* p = (char*)d_ws;
    int*   cursors  = (int*)p;   p += 1024;
    int*   cbase    = (int*)p;   p += 1024;
    int*   rowstart = (int*)p;   p += (size_t)N * 4;
    int*   cnt      = (int*)p;   p += (size_t)N * 4;
    float* dinv     = (float*)p; p += (size_t)N * 4;
    unsigned short* W1s = (unsigned short*)p; p += IN_CH * HID * 2;
    int2*  csr      = (int2*)p;  p += (size_t)Et * 8;
    uint2* packed   = (uint2*)p;               // nbk*CAP*8 = 32.1 MB
    float* h1s      = (float*)p;               // 6.4 MB (aliases packed)
    float* out1s    = h1s + (size_t)N * HID;   // 6.4 MB

    k_init<<<1, 256, 0, stream>>>(cursors, nbk);
    k_prep<<<1, 256, 0, stream>>>(W1, W1s);
    k_partition<<<(Et + PE - 1) / PE, 1024, 0, stream>>>(ei1, w1, E1, ei2, w2, E2,
                                                         cursors, packed, Et);
    k_bucket_scan<<<1, 256, 0, stream>>>(cursors, cbase, nbk);
    k_buildcsr<<<nbk, 1024, 0, stream>>>(packed, cursors, cbase,
                                         rowstart, cnt, dinv, csr, N);
    int tiles = (N + 15) / 16;
    k_gemm1<<<(tiles + 3) / 4, 256, 0, stream>>>(x, W1s, dinv, h1s, N);
    k_agg1<<<(N + 3) / 4, 256, 0, stream>>>(h1s, csr, rowstart, cnt, dinv, b1, out1s, N);
    k_layer2<<<(N + 3) / 4, 256, 0, stream>>>(out1s, csr, rowstart, cnt, dinv, W2, b2, out, N);
}

// Round 5
// 502.213 us; speedup vs baseline: 2.1205x; 1.0298x over previous
//
#include <hip/hip_runtime.h>
#include <hip/hip_bf16.h>
#include <hip/hip_fp16.h>

#define IN_CH 512
#define HID 16
#define OUT_CH 64
#define CAP 20480   // bucket capacity: mean 16384, sigma ~128 -> +32 sigma
#define PE 8192     // edges per partition block

typedef __attribute__((ext_vector_type(8))) short bf16x8;
typedef __attribute__((ext_vector_type(4))) float f32x4;

__device__ inline unsigned short f2bf(float f) {   // RNE truncate to bf16
    unsigned int u = __float_as_uint(f);
    return (unsigned short)((u + 0x7fffu + ((u >> 16) & 1u)) >> 16);
}

union A8 { bf16x8 v; short2 p[4]; };
__device__ inline short2 pk2(float a, float b) {
    union { __hip_bfloat162 h; short2 s; } u;
    u.h = __float22bfloat162_rn(make_float2(a, b));
    return u.s;
}

// ---------------- init bucket cursors ----------------
__global__ void k_init(int* __restrict__ cursors, int nbk) {
    int i = threadIdx.x;
    if (i < nbk) cursors[i] = i * CAP;
}

// ---------------- Phase 1: partition edges into 512-node buckets ----------------
// Single global read of the edge list (rows held in regs). Edges are sorted by
// bucket into an LDS staging buffer, then written out bucket-contiguous ->
// coalesced global stores. (Proven: 541 -> 517 us vs the old 2-pass version.)
__global__ __launch_bounds__(1024) void k_partition(const int* __restrict__ ei1, const float* __restrict__ w1, int E1,
                                                    const int* __restrict__ ei2, const float* __restrict__ w2, int E2,
                                                    int* __restrict__ cursors,
                                                    uint2* __restrict__ packed, int Et) {
    __shared__ int hist[256];
    __shared__ int sc[256];
    __shared__ int lbase[256];
    __shared__ int gbase[256];
    __shared__ int lcur[256];
    __shared__ uint2 stage[PE];          // 64 KB
    __shared__ unsigned char bkt[PE];    // slot -> bucket (8 KB)
    int tid = threadIdx.x;
    int e0 = blockIdx.x * PE;
    if (tid < 256) hist[tid] = 0;
    __syncthreads();
    int r[8];
    #pragma unroll
    for (int j = 0; j < 8; ++j) {
        int e = e0 + j * 1024 + tid;
        int rr = -1;
        if (e < Et) rr = (e < E1) ? ei1[e] : ei2[e - E1];
        r[j] = rr;
        if (rr >= 0) atomicAdd(&hist[rr >> 9], 1);
    }
    __syncthreads();
    int v = (tid < 256) ? hist[tid] : 0;
    if (tid < 256) sc[tid] = v;
    __syncthreads();
    for (int off = 1; off < 256; off <<= 1) {
        int t = (tid >= off && tid < 256) ? sc[tid - off] : 0;
        __syncthreads();
        if (tid < 256) sc[tid] += t;
        __syncthreads();
    }
    if (tid < 256) {
        int ex = sc[tid] - v;            // exclusive local base
        lbase[tid] = ex;
        lcur[tid] = ex;
        gbase[tid] = (v > 0) ? atomicAdd(&cursors[tid], v) : 0;  // one global atomic per (block,bucket)
    }
    __syncthreads();
    // place cols/weights into LDS stage, bucket-sorted
    #pragma unroll
    for (int j = 0; j < 8; ++j) {
        if (r[j] >= 0) {
            int e = e0 + j * 1024 + tid;
            int cc; float ww;
            if (e < E1) { cc = ei1[e + E1]; ww = w1[e]; }
            else        { int f = e - E1; cc = ei2[f + E2]; ww = w2[f]; }
            int bk = r[j] >> 9;
            int pos = atomicAdd(&lcur[bk], 1);
            stage[pos] = make_uint2(((unsigned)(r[j] & 511) << 17) | (unsigned)cc,
                                    __float_as_uint(ww));
            bkt[pos] = (unsigned char)bk;
        }
    }
    __syncthreads();
    // coalesced write-out: consecutive slots in the same bucket hit consecutive
    // global addresses (bucket runs avg ~32 entries)
    int nv = min(PE, Et - e0);
    for (int i = tid; i < nv; i += 1024) {
        int bk = bkt[i];
        packed[(size_t)gbase[bk] + (i - lbase[bk])] = stage[i];
    }
}

// ---------------- Phase 2: bucket totals -> dense CSR base offsets ----------------
__global__ void k_bucket_scan(const int* __restrict__ cursors, int* __restrict__ cbase, int nbk) {
    __shared__ int s[256];
    int tid = threadIdx.x;
    int v = (tid < nbk) ? (cursors[tid] - tid * CAP) : 0;
    s[tid] = v;
    __syncthreads();
    for (int off = 1; off < 256; off <<= 1) {
        int t = (tid >= off) ? s[tid - off] : 0;
        __syncthreads();
        s[tid] += t;
        __syncthreads();
    }
    if (tid < nbk) cbase[tid] = s[tid] - v;  // exclusive
}

// ---------------- Phase 3: per-bucket CSR build (pure streaming) ----------------
__global__ __launch_bounds__(1024) void k_buildcsr(const uint2* __restrict__ packed,
                                                   const int* __restrict__ cursors,
                                                   const int* __restrict__ cbase,
                                                   int2* __restrict__ rowmeta,
                                                   float* __restrict__ dinv, int2* __restrict__ csr, int N) {
    __shared__ int lcnt[512];
    __shared__ int lcur[512];
    __shared__ int lscan[512];
    __shared__ float ldeg[512];
    int b = blockIdx.x, tid = threadIdx.x;
    int M = cursors[b] - b * CAP;
    const uint2* pk = packed + (size_t)b * CAP;
    if (tid < 512) { lcnt[tid] = 0; ldeg[tid] = 0.f; }
    __syncthreads();
    for (int i = tid; i < M; i += 1024) atomicAdd(&lcnt[pk[i].x >> 17], 1);
    __syncthreads();
    int v = (tid < 512) ? lcnt[tid] : 0;
    if (tid < 512) lscan[tid] = v;
    __syncthreads();
    for (int off = 1; off < 512; off <<= 1) {
        int t = (tid >= off && tid < 512) ? lscan[tid - off] : 0;
        __syncthreads();
        if (tid < 512) lscan[tid] += t;
        __syncthreads();
    }
    int cb = cbase[b];
    if (tid < 512) {
        int ex = lscan[tid] - v;
        lcur[tid] = cb + ex;          // direct global cursor
        int node = b * 512 + tid;
        if (node < N) rowmeta[node] = make_int2(cb + ex, v);
    }
    __syncthreads();
    for (int i = tid; i < M; i += 1024) {
        uint2 u = pk[i];
        int lr = u.x >> 17;
        int c  = u.x & 0x1FFFF;
        int p = atomicAdd(&lcur[lr], 1);
        csr[p] = make_int2(c, (int)u.y);
        atomicAdd(&ldeg[lr], __uint_as_float(u.y));
    }
    __syncthreads();
    if (tid < 512) {
        int node = b * 512 + tid;
        if (node < N) {
            float d = ldeg[tid];
            dinv[node] = (d > 0.f) ? rsqrtf(fmaxf(d, 1e-12f)) : 0.f;
        }
    }
}

// ---------------- prep: W1 -> bf16, swizzled into B-fragment order ----------------
// W1s[(kc*64+lane)*8 + j] = bf16(W1[(kc*32 + (lane>>4)*8 + j)*16 + (lane&15)])
__global__ void k_prep(const float* __restrict__ W1, unsigned short* __restrict__ W1s) {
    for (int p = threadIdx.x; p < 1024; p += 256) {
        int kc = p >> 6, lane = p & 63;
        int q = lane >> 4, m = lane & 15;
        int k0 = kc * 32 + q * 8;
        unsigned v[8];
        #pragma unroll
        for (int j = 0; j < 8; ++j) v[j] = f2bf(W1[(k0 + j) * HID + m]);
        uint4 o;
        o.x = v[0] | (v[1] << 16); o.y = v[2] | (v[3] << 16);
        o.z = v[4] | (v[5] << 16); o.w = v[6] | (v[7] << 16);
        ((uint4*)W1s)[p] = o;
    }
}

// ---------------- h1s = f16(dinv * (x @ W1)) via MFMA bf16 ----------------
__global__ __launch_bounds__(256) void k_gemm1(const float* __restrict__ x,
                                               const unsigned short* __restrict__ W1s,
                                               const float* __restrict__ dinv,
                                               __half* __restrict__ h1s, int n) {
    int wave = threadIdx.x >> 6, lane = threadIdx.x & 63;
    int tiles = (n + 15) >> 4;
    int t = blockIdx.x * 4 + wave;
    if (t >= tiles) return;

    int m = lane & 15, quad = lane >> 4;

    const bf16x8* Wv = (const bf16x8*)W1s;
    bf16x8 Bf[16];
    #pragma unroll
    for (int kc = 0; kc < 16; ++kc) Bf[kc] = Wv[kc * 64 + lane];   // 16B contiguous

    int row = t * 16 + m;
    int rl = min(row, n - 1);
    const float4* xr = (const float4*)(x + (size_t)rl * IN_CH + quad * 8);

    f32x4 acc = {0.f, 0.f, 0.f, 0.f};
    #pragma unroll
    for (int kc = 0; kc < 16; ++kc) {
        float4 v0 = xr[kc * 8];
        float4 v1 = xr[kc * 8 + 1];
        A8 a;
        a.p[0] = pk2(v0.x, v0.y); a.p[1] = pk2(v0.z, v0.w);
        a.p[2] = pk2(v1.x, v1.y); a.p[3] = pk2(v1.z, v1.w);
        acc = __builtin_amdgcn_mfma_f32_16x16x32_bf16(a.v, Bf[kc], acc, 0, 0, 0);
    }

    int base = t * 16 + quad * 4;
    #pragma unroll
    for (int r = 0; r < 4; ++r) {
        int orow = base + r;
        if (orow < n) h1s[(size_t)orow * HID + m] = __float2half(dinv[orow] * acc[r]);
    }
}

// ---------------- out1s = f16(dinv * relu(dinv*aggregate(h1s) + b1)) ----------------
// lane = (slot=lane>>2 edge slot, c4=lane&3 channel quad). 16 edges in flight,
// 8B f16x4 gathers (32B line per edge, halved from 64B f32 rows).
__global__ __launch_bounds__(256) void k_agg1(const __half* __restrict__ h1s,
                                              const int2* __restrict__ csr,
                                              const int2* __restrict__ rowmeta,
                                              const float* __restrict__ dinv,
                                              const float* __restrict__ b1,
                                              __half* __restrict__ out1s, int n) {
    int wave = threadIdx.x >> 6, lane = threadIdx.x & 63;
    int node = blockIdx.x * 4 + wave;
    if (node >= n) return;
    int slot = lane >> 2, c4 = lane & 3;
    int2 rm = rowmeta[node];
    const int2* ce = csr + rm.x;
    int deg = rm.y;
    f32x4 acc = {0.f, 0.f, 0.f, 0.f};
    for (int i = slot; i < deg; i += 16) {
        int2 e = ce[i];
        float w = __int_as_float(e.y);
        uint2 raw = ((const uint2*)(h1s + (size_t)e.x * HID))[c4];
        float2 f01 = __half22float2(*(const __half2*)&raw.x);
        float2 f23 = __half22float2(*(const __half2*)&raw.y);
        acc[0] = fmaf(w, f01.x, acc[0]); acc[1] = fmaf(w, f01.y, acc[1]);
        acc[2] = fmaf(w, f23.x, acc[2]); acc[3] = fmaf(w, f23.y, acc[3]);
    }
    #pragma unroll
    for (int off = 4; off < 64; off <<= 1) {
        acc[0] += __shfl_xor(acc[0], off, 64);
        acc[1] += __shfl_xor(acc[1], off, 64);
        acc[2] += __shfl_xor(acc[2], off, 64);
        acc[3] += __shfl_xor(acc[3], off, 64);
    }
    if (lane < 4) {
        float dv = dinv[node];
        float4 bb = ((const float4*)b1)[c4];
        float4 o;
        o.x = fmaxf(fmaf(dv, acc[0], bb.x), 0.f) * dv;
        o.y = fmaxf(fmaf(dv, acc[1], bb.y), 0.f) * dv;
        o.z = fmaxf(fmaf(dv, acc[2], bb.z), 0.f) * dv;
        o.w = fmaxf(fmaf(dv, acc[3], bb.w), 0.f) * dv;
        __half2 p01 = __float22half2_rn(make_float2(o.x, o.y));
        __half2 p23 = __float22half2_rn(make_float2(o.z, o.w));
        uint2 st;
        st.x = *(unsigned*)&p01; st.y = *(unsigned*)&p23;
        ((uint2*)(out1s + (size_t)node * HID))[c4] = st;
    }
}

// ---------------- layer2: agg(out1s) -> 16->64 GEMM -> log_softmax ----------------
__global__ __launch_bounds__(256) void k_layer2(const __half* __restrict__ out1s,
                                                const int2* __restrict__ csr,
                                                const int2* __restrict__ rowmeta,
                                                const float* __restrict__ dinv,
                                                const float* __restrict__ W2,
                                                const float* __restrict__ b2,
                                                float* __restrict__ out, int n) {
    __shared__ float W2l[HID * OUT_CH];
    for (int i = threadIdx.x; i < HID * OUT_CH; i += 256) W2l[i] = W2[i];
    __syncthreads();

    int wave = threadIdx.x >> 6, lane = threadIdx.x & 63;
    int node = blockIdx.x * 4 + wave;
    if (node >= n) return;
    int slot = lane >> 2, c4 = lane & 3;
    int2 rm = rowmeta[node];
    const int2* ce = csr + rm.x;
    int deg = rm.y;
    f32x4 acc = {0.f, 0.f, 0.f, 0.f};
    for (int i = slot; i < deg; i += 16) {
        int2 e = ce[i];
        float w = __int_as_float(e.y);
        uint2 raw = ((const uint2*)(out1s + (size_t)e.x * HID))[c4];
        float2 f01 = __half22float2(*(const __half2*)&raw.x);
        float2 f23 = __half22float2(*(const __half2*)&raw.y);
        acc[0] = fmaf(w, f01.x, acc[0]); acc[1] = fmaf(w, f01.y, acc[1]);
        acc[2] = fmaf(w, f23.x, acc[2]); acc[3] = fmaf(w, f23.y, acc[3]);
    }
    #pragma unroll
    for (int off = 4; off < 64; off <<= 1) {
        acc[0] += __shfl_xor(acc[0], off, 64);
        acc[1] += __shfl_xor(acc[1], off, 64);
        acc[2] += __shfl_xor(acc[2], off, 64);
        acc[3] += __shfl_xor(acc[3], off, 64);
    }
    float dv = dinv[node];
    acc[0] *= dv; acc[1] *= dv; acc[2] *= dv; acc[3] *= dv;
    // lane j needs all 16 agg values: lane gg (gg<4) holds channels 4gg..4gg+3
    float v = b2[lane];
    #pragma unroll
    for (int gg = 0; gg < 4; ++gg) {
        float a0 = __shfl(acc[0], gg, 64);
        float a1 = __shfl(acc[1], gg, 64);
        float a2 = __shfl(acc[2], gg, 64);
        float a3 = __shfl(acc[3], gg, 64);
        v = fmaf(a0, W2l[(4 * gg + 0) * OUT_CH + lane], v);
        v = fmaf(a1, W2l[(4 * gg + 1) * OUT_CH + lane], v);
        v = fmaf(a2, W2l[(4 * gg + 2) * OUT_CH + lane], v);
        v = fmaf(a3, W2l[(4 * gg + 3) * OUT_CH + lane], v);
    }
    float m = v;
    #pragma unroll
    for (int off = 32; off; off >>= 1) m = fmaxf(m, __shfl_xor(m, off, 64));
    float ex = __expf(v - m);
    float s = ex;
    #pragma unroll
    for (int off = 32; off; off >>= 1) s += __shfl_xor(s, off, 64);
    out[(size_t)node * OUT_CH + lane] = (v - m) - __logf(s);
}

extern "C" void kernel_launch(void* const* d_in, const int* in_sizes, int n_in,
                              void* d_out, int out_size, void* d_ws, size_t ws_size,
                              hipStream_t stream) {
    const float* x   = (const float*)d_in[0];
    const int*   ei1 = (const int*)d_in[1];
    const float* w1  = (const float*)d_in[2];
    const int*   ei2 = (const int*)d_in[3];
    const float* w2  = (const float*)d_in[4];
    const float* W1  = (const float*)d_in[5];
    const float* b1  = (const float*)d_in[6];
    const float* W2  = (const float*)d_in[7];
    const float* b2  = (const float*)d_in[8];
    int N  = in_sizes[0] / IN_CH;
    int E1 = in_sizes[2];
    int E2 = in_sizes[4];
    int Et = E1 + E2;
    float* out = (float*)d_out;
    int nbk = (N + 511) >> 9;   // 196 buckets of 512 nodes

    // workspace layout; packed (dead after k_buildcsr) aliases h1s+out1s
    char* p = (char*)d_ws;
    int*   cursors  = (int*)p;   p += 1024;
    int*   cbase    = (int*)p;   p += 1024;
    int2*  rowmeta  = (int2*)p;  p += (size_t)N * 8;
    float* dinv     = (float*)p; p += (size_t)N * 4;
    unsigned short* W1s = (unsigned short*)p; p += IN_CH * HID * 2;
    int2*  csr      = (int2*)p;  p += (size_t)Et * 8;
    uint2* packed   = (uint2*)p;               // nbk*CAP*8 = 32.1 MB
    __half* h1s     = (__half*)p;              // 3.2 MB (aliases packed)
    __half* out1s   = h1s + (size_t)N * HID;   // 3.2 MB

    k_init<<<1, 256, 0, stream>>>(cursors, nbk);
    k_prep<<<1, 256, 0, stream>>>(W1, W1s);
    k_partition<<<(Et + PE - 1) / PE, 1024, 0, stream>>>(ei1, w1, E1, ei2, w2, E2,
                                                         cursors, packed, Et);
    k_bucket_scan<<<1, 256, 0, stream>>>(cursors, cbase, nbk);
    k_buildcsr<<<nbk, 1024, 0, stream>>>(packed, cursors, cbase,
                                         rowmeta, dinv, csr, N);
    int tiles = (N + 15) / 16;
    k_gemm1<<<(tiles + 3) / 4, 256, 0, stream>>>(x, W1s, dinv, h1s, N);
    k_agg1<<<(N + 3) / 4, 256, 0, stream>>>(h1s, csr, rowmeta, dinv, b1, out1s, N);
    k_layer2<<<(N + 3) / 4, 256, 0, stream>>>(out1s, csr, rowmeta, dinv, W2, b2, out, N);
}